// Round 11
// baseline (69.041 us; speedup 1.0000x reference)
//
#include <hip/hip_runtime.h>
#include <hip/hip_bf16.h>

// Poincare pairwise distance, c=1:
//   d(x,p) = acosh(1 + 2*||x-p||^2 / ((1-||x||^2)(1-||p||^2)))
// B=16384, N=4096, D=64. Output 16384x4096 f32 (256 MiB) -> write-bound.
//
// Round 11: L2-MISS READ minimization. band = bid&7 -> each XCD owns one
// 512-proto n-band, so its 64KB proto-image slice + 4KB norm slices stay
// permanently L2-hot (reuse distance = 1 block) despite the write-stream
// thrash. Block = 128 emb rows x 512 protos: emb tile read ONCE per block,
// 4 proto tiles looped from double-buffered LDS with register prefetch
// (issue-early / write-late). Chip-wide L2-miss reads ~18MB (was ~139MB).

constexpr int BATCH = 16384;
constexpr int NCON  = 4096;
constexpr int DIM   = 64;
constexpr int TM    = 128;
constexpr int TN    = 128;          // protos per tile
constexpr int NTPB  = 4;            // proto tiles per block (512-band)

// ws layout (bytes), 16B-aligned (identical bytes to rounds 6/8/10):
constexpr size_t WS_EMB   = 0;                        // 2 MiB  (bf16 swizzled emb images)
constexpr size_t WS_PROTO = (size_t)2 << 20;          // 512 KiB (bf16 swizzled proto images)
constexpr size_t WS_X2    = WS_PROTO + (512u << 10);  // f32[16384]
constexpr size_t WS_CROW  = WS_X2   + 64u * 1024;     // f32[16384]
constexpr size_t WS_P2    = WS_CROW + 64u * 1024;     // f32[4096]
constexpr size_t WS_RP    = WS_P2   + 16u * 1024;     // f32[4096]

typedef float  f32x4  __attribute__((ext_vector_type(4)));
typedef __bf16 bf16x8 __attribute__((ext_vector_type(8)));

// ---------------- pre-pass (unchanged from rounds 6/8/10) ----------------
__global__ __launch_bounds__(256)
void prepass_kernel(const float* __restrict__ emb,
                    const float* __restrict__ proto,
                    char* __restrict__ ws)
{
    int gid = blockIdx.x * 256 + threadIdx.x;
    if (gid < 131072) {
        int c = gid;
        int mt = c >> 9, within = c & 511;          // 64-row half-tiles
        int e0  = within * 8;
        int row = e0 >> 6;
        int k0  = (e0 & 63) ^ ((row & 7) << 3);
        const float* src = emb + (size_t)(mt * 64 + row) * DIM + k0;
        f32x4 a = *reinterpret_cast<const f32x4*>(src);
        f32x4 b = *reinterpret_cast<const f32x4*>(src + 4);
        bf16x8 v;
        v[0]=(__bf16)a.x; v[1]=(__bf16)a.y; v[2]=(__bf16)a.z; v[3]=(__bf16)a.w;
        v[4]=(__bf16)b.x; v[5]=(__bf16)b.y; v[6]=(__bf16)b.z; v[7]=(__bf16)b.w;
        *reinterpret_cast<bf16x8*>(ws + WS_EMB + (size_t)c * 16) = v;
    } else if (gid < 163840) {
        int c = gid - 131072;
        int nt = c >> 10, within = c & 1023;        // 128-row tiles
        int e0  = within * 8;
        int row = e0 >> 6;
        int k0  = (e0 & 63) ^ ((row & 7) << 3);
        const float* src = proto + (size_t)(nt * 128 + row) * DIM + k0;
        f32x4 a = *reinterpret_cast<const f32x4*>(src);
        f32x4 b = *reinterpret_cast<const f32x4*>(src + 4);
        bf16x8 v;
        v[0]=(__bf16)a.x; v[1]=(__bf16)a.y; v[2]=(__bf16)a.z; v[3]=(__bf16)a.w;
        v[4]=(__bf16)b.x; v[5]=(__bf16)b.y; v[6]=(__bf16)b.z; v[7]=(__bf16)b.w;
        *reinterpret_cast<bf16x8*>(ws + WS_PROTO + (size_t)c * 16) = v;
    } else if (gid < 180224) {
        int r = gid - 163840;
        const f32x4* src = reinterpret_cast<const f32x4*>(emb + (size_t)r * DIM);
        float s = 0.0f;
        #pragma unroll
        for (int i = 0; i < 16; ++i) {
            f32x4 v = src[i];
            s += v.x*v.x + v.y*v.y + v.z*v.z + v.w*v.w;
        }
        reinterpret_cast<float*>(ws + WS_X2)[r]   = s;
        reinterpret_cast<float*>(ws + WS_CROW)[r] = 2.0f * __builtin_amdgcn_rcpf(1.0f - s);
    } else if (gid < 184320) {
        int r = gid - 180224;
        const f32x4* src = reinterpret_cast<const f32x4*>(proto + (size_t)r * DIM);
        float s = 0.0f;
        #pragma unroll
        for (int i = 0; i < 16; ++i) {
            f32x4 v = src[i];
            s += v.x*v.x + v.y*v.y + v.z*v.z + v.w*v.w;
        }
        reinterpret_cast<float*>(ws + WS_P2)[r] = s;
        reinterpret_cast<float*>(ws + WS_RP)[r] = __builtin_amdgcn_rcpf(1.0f - s);
    }
}

// ---------------- main kernel ----------------
// Grid 1024 = 128 m-tiles x 8 n-bands. band = bid&7 (one band per XCD).
// Block: stage emb tile once; loop 4 proto tiles, double-buffered LDS with
// register prefetch. 4 waves; wave owns 32 emb rows x 128 protos. 3 blk/CU.
__global__ __launch_bounds__(256, 3)
void poincare_pairwise_kernel(const char* __restrict__ ws,
                              float* __restrict__ out)
{
    __shared__ __bf16 As[TM * DIM];        // 16 KiB (emb tile, pre-swizzled)
    __shared__ __bf16 Bs[2][TN * DIM];     // 32 KiB (proto tiles, dbuf)

    const int tid  = threadIdx.x;
    const int bid  = blockIdx.x;
    const int band = bid & 7;              // n-band -> XCD
    const int mt   = bid >> 3;             // 0..127
    const int m0   = mt * TM;
    const int n0   = band * (TN * NTPB);   // 512-wide band

    // ---------- stage emb tile + proto tile 0 (pure linear uint4 copy) ----------
    {
        const uint4* esrc = reinterpret_cast<const uint4*>(ws + WS_EMB + (size_t)mt * 16384);
        const uint4* psrc = reinterpret_cast<const uint4*>(ws + WS_PROTO + (size_t)(band * NTPB) * 16384);
        uint4* edst = reinterpret_cast<uint4*>(As);
        uint4* pdst = reinterpret_cast<uint4*>(Bs[0]);
        #pragma unroll
        for (int i = 0; i < 4; ++i) {
            edst[i * 256 + tid] = esrc[i * 256 + tid];
            pdst[i * 256 + tid] = psrc[i * 256 + tid];
        }
    }

    const int lane = tid & 63;
    const int wid  = tid >> 6;             // wave -> 32-row emb strip
    const int lr   = lane & 15;
    const int g    = lane >> 4;
    const int lk   = g * 8;

    // per-lane row params (issued while staging is in flight)
    float  x2[2], crow[2];
    float* rowp[2];
    #pragma unroll
    for (int rf = 0; rf < 2; ++rf) {
        int xrow = wid * 32 + rf * 16 + lr;
        x2[rf]   = reinterpret_cast<const float*>(ws + WS_X2)[m0 + xrow];
        crow[rf] = reinterpret_cast<const float*>(ws + WS_CROW)[m0 + xrow];
        rowp[rf] = out + (size_t)(m0 + xrow) * NCON + n0;
    }
    const float* p2a = reinterpret_cast<const float*>(ws + WS_P2) + n0;
    const float* rpa = reinterpret_cast<const float*>(ws + WS_RP) + n0;

    __syncthreads();

    // ---------- emb fragments (once) ----------
    bf16x8 xfrag[2][2];                    // [rf][kk]
    #pragma unroll
    for (int rf = 0; rf < 2; ++rf) {
        int xrow = wid * 32 + rf * 16 + lr;
        #pragma unroll
        for (int kk = 0; kk < 2; ++kk) {
            int ke = (kk * 32 + lk) ^ ((xrow & 7) << 3);
            xfrag[rf][kk] = *reinterpret_cast<const bf16x8*>(&As[xrow * DIM + ke]);
        }
    }

    // ---------- loop 4 proto tiles ----------
    for (int t = 0; t < NTPB; ++t) {
        const int cur = t & 1;

        // prefetch next proto tile to registers (issued before compute)
        uint4 pv[4];
        if (t < NTPB - 1) {
            const uint4* psrc = reinterpret_cast<const uint4*>(
                ws + WS_PROTO + (size_t)(band * NTPB + t + 1) * 16384);
            #pragma unroll
            for (int i = 0; i < 4; ++i)
                pv[i] = psrc[i * 256 + tid];
        }

        // MFMA: wave = 32 emb rows x 128 protos
        f32x4 acc[2][8] = {};              // [rf][pf]
        #pragma unroll
        for (int kk = 0; kk < 2; ++kk) {
            bf16x8 pfrag[8];
            #pragma unroll
            for (int pf = 0; pf < 8; ++pf) {
                int prow = pf * 16 + lr;
                int kep  = (kk * 32 + lk) ^ ((prow & 7) << 3);
                pfrag[pf] = *reinterpret_cast<const bf16x8*>(&Bs[cur][prow * DIM + kep]);
            }
            #pragma unroll
            for (int pf = 0; pf < 8; ++pf) {
                acc[0][pf] = __builtin_amdgcn_mfma_f32_16x16x32_bf16(pfrag[pf], xfrag[0][kk], acc[0][pf], 0, 0, 0);
                acc[1][pf] = __builtin_amdgcn_mfma_f32_16x16x32_bf16(pfrag[pf], xfrag[1][kk], acc[1][pf], 0, 0, 0);
            }
        }

        // epilogue: poly acosh + store
        // D layout: col = lane&15 -> emb row (lr); row = g*4+j -> proto idx.
        // d = sqrt(tt) * P(tt), P cubic fit of acosh(1+t)/sqrt(t) on [0,4].
        const int cb = t * TN;
        #pragma unroll
        for (int pf = 0; pf < 8; ++pf) {
            int   col = cb + pf * 16 + g * 4;
            f32x4 p2  = *reinterpret_cast<const f32x4*>(p2a + col);
            f32x4 rp  = *reinterpret_cast<const f32x4*>(rpa + col);
            #pragma unroll
            for (int rf = 0; rf < 2; ++rf) {
                f32x4 dv;
                #pragma unroll
                for (int j = 0; j < 4; ++j) {
                    float sq = fmaxf(x2[rf] + p2[j] - 2.0f * acc[rf][pf][j], 0.0f);
                    float tt = sq * (crow[rf] * rp[j]);
                    float u  = __builtin_amdgcn_sqrtf(tt);
                    float pl = fmaf(fmaf(fmaf(-0.0013415f, tt, 0.0164700f),
                                         tt, -0.1113059f),
                                    tt, 1.4134377f);
                    dv[j]    = u * pl;
                }
                *reinterpret_cast<f32x4*>(rowp[rf] + col) = dv;
            }
        }

        // write prefetched tile (write-late) + single barrier per tile
        if (t < NTPB - 1) {
            uint4* pdst = reinterpret_cast<uint4*>(Bs[cur ^ 1]);
            #pragma unroll
            for (int i = 0; i < 4; ++i)
                pdst[i * 256 + tid] = pv[i];
            __syncthreads();
        }
    }
}

extern "C" void kernel_launch(void* const* d_in, const int* in_sizes, int n_in,
                              void* d_out, int out_size, void* d_ws, size_t ws_size,
                              hipStream_t stream) {
    const float* emb   = (const float*)d_in[0];
    const float* proto = (const float*)d_in[1];
    float* out = (float*)d_out;
    char* ws   = (char*)d_ws;

    prepass_kernel<<<720, 256, 0, stream>>>(emb, proto, ws);    // 184320 threads
    poincare_pairwise_kernel<<<1024, 256, 0, stream>>>(ws, out); // 128 m x 8 bands
}

// Round 12
// 60.909 us; speedup vs baseline: 1.1335x; 1.1335x over previous
//
#include <hip/hip_runtime.h>
#include <hip/hip_bf16.h>

// Poincare pairwise distance, c=1:
//   d(x,p) = acosh(1 + 2*||x-p||^2 / ((1-||x||^2)(1-||p||^2)))
// B=16384, N=4096, D=64. Output 16384x4096 f32 (256 MiB) -> write-bound.
//
// Round 12 = R8/R10 skeleton (prepass images, pure-copy staging, ONE
// barrier, barrier-free epilogue, poly acosh) with a 256x128 tile:
// grid 2048, reads 96MB (was 128MB at 128x128). acc[4][8]=128 VGPR ->
// launch_bounds(256,2), 2 blocks/CU, zero tail (4 uniform generations).

constexpr int BATCH = 16384;
constexpr int NCON  = 4096;
constexpr int DIM   = 64;
constexpr int TM    = 256;
constexpr int TN    = 128;

// ws layout (bytes), 16B-aligned (identical bytes to rounds 6/8/10):
constexpr size_t WS_EMB   = 0;                        // 2 MiB  (bf16 swizzled emb images)
constexpr size_t WS_PROTO = (size_t)2 << 20;          // 512 KiB (bf16 swizzled proto images)
constexpr size_t WS_X2    = WS_PROTO + (512u << 10);  // f32[16384]
constexpr size_t WS_CROW  = WS_X2   + 64u * 1024;     // f32[16384]
constexpr size_t WS_P2    = WS_CROW + 64u * 1024;     // f32[4096]
constexpr size_t WS_RP    = WS_P2   + 16u * 1024;     // f32[4096]

typedef float  f32x4  __attribute__((ext_vector_type(4)));
typedef __bf16 bf16x8 __attribute__((ext_vector_type(8)));

// ---------------- pre-pass (unchanged from rounds 6/8/10) ----------------
__global__ __launch_bounds__(256)
void prepass_kernel(const float* __restrict__ emb,
                    const float* __restrict__ proto,
                    char* __restrict__ ws)
{
    int gid = blockIdx.x * 256 + threadIdx.x;
    if (gid < 131072) {
        int c = gid;
        int mt = c >> 9, within = c & 511;          // 64-row half-tiles
        int e0  = within * 8;
        int row = e0 >> 6;
        int k0  = (e0 & 63) ^ ((row & 7) << 3);
        const float* src = emb + (size_t)(mt * 64 + row) * DIM + k0;
        f32x4 a = *reinterpret_cast<const f32x4*>(src);
        f32x4 b = *reinterpret_cast<const f32x4*>(src + 4);
        bf16x8 v;
        v[0]=(__bf16)a.x; v[1]=(__bf16)a.y; v[2]=(__bf16)a.z; v[3]=(__bf16)a.w;
        v[4]=(__bf16)b.x; v[5]=(__bf16)b.y; v[6]=(__bf16)b.z; v[7]=(__bf16)b.w;
        *reinterpret_cast<bf16x8*>(ws + WS_EMB + (size_t)c * 16) = v;
    } else if (gid < 163840) {
        int c = gid - 131072;
        int nt = c >> 10, within = c & 1023;        // 128-row tiles
        int e0  = within * 8;
        int row = e0 >> 6;
        int k0  = (e0 & 63) ^ ((row & 7) << 3);
        const float* src = proto + (size_t)(nt * 128 + row) * DIM + k0;
        f32x4 a = *reinterpret_cast<const f32x4*>(src);
        f32x4 b = *reinterpret_cast<const f32x4*>(src + 4);
        bf16x8 v;
        v[0]=(__bf16)a.x; v[1]=(__bf16)a.y; v[2]=(__bf16)a.z; v[3]=(__bf16)a.w;
        v[4]=(__bf16)b.x; v[5]=(__bf16)b.y; v[6]=(__bf16)b.z; v[7]=(__bf16)b.w;
        *reinterpret_cast<bf16x8*>(ws + WS_PROTO + (size_t)c * 16) = v;
    } else if (gid < 180224) {
        int r = gid - 163840;
        const f32x4* src = reinterpret_cast<const f32x4*>(emb + (size_t)r * DIM);
        float s = 0.0f;
        #pragma unroll
        for (int i = 0; i < 16; ++i) {
            f32x4 v = src[i];
            s += v.x*v.x + v.y*v.y + v.z*v.z + v.w*v.w;
        }
        reinterpret_cast<float*>(ws + WS_X2)[r]   = s;
        reinterpret_cast<float*>(ws + WS_CROW)[r] = 2.0f * __builtin_amdgcn_rcpf(1.0f - s);
    } else if (gid < 184320) {
        int r = gid - 180224;
        const f32x4* src = reinterpret_cast<const f32x4*>(proto + (size_t)r * DIM);
        float s = 0.0f;
        #pragma unroll
        for (int i = 0; i < 16; ++i) {
            f32x4 v = src[i];
            s += v.x*v.x + v.y*v.y + v.z*v.z + v.w*v.w;
        }
        reinterpret_cast<float*>(ws + WS_P2)[r] = s;
        reinterpret_cast<float*>(ws + WS_RP)[r] = __builtin_amdgcn_rcpf(1.0f - s);
    }
}

// ---------------- main kernel ----------------
// Grid 2048 = 64 m-tiles x 32 n-tiles. mt owned by one XCD (emb read once
// per XCD); 8 consecutive blocks within an XCD share nt (proto L2-hot).
// 4 waves; wave owns 64 emb rows x 128 protos. 2 blocks/CU.
__global__ __launch_bounds__(256, 2)
void poincare_pairwise_kernel(const char* __restrict__ ws,
                              float* __restrict__ out)
{
    __shared__ __bf16 As[TM * DIM];   // 32 KiB (emb tile image)
    __shared__ __bf16 Bs[TN * DIM];   // 16 KiB (proto tile image)

    const int tid = threadIdx.x;
    const int bid = blockIdx.x;
    const int xcd = bid & 7;
    const int q   = bid >> 3;          // 0..255
    const int mt  = xcd * 8 + (q & 7); // 0..63, one XCD per mt
    const int nt  = q >> 3;            // 0..31
    const int m0  = mt * TM;
    const int n0  = nt * TN;

    // ---------- staging: pure linear uint4 copy ----------
    {
        const uint4* esrc = reinterpret_cast<const uint4*>(ws + WS_EMB + (size_t)mt * 32768);
        uint4* edst = reinterpret_cast<uint4*>(As);
        #pragma unroll
        for (int i = 0; i < 8; ++i)
            edst[i * 256 + tid] = esrc[i * 256 + tid];
        const uint4* psrc = reinterpret_cast<const uint4*>(ws + WS_PROTO + (size_t)nt * 16384);
        uint4* pdst = reinterpret_cast<uint4*>(Bs);
        #pragma unroll
        for (int i = 0; i < 4; ++i)
            pdst[i * 256 + tid] = psrc[i * 256 + tid];
    }

    const int lane = tid & 63;
    const int wid  = tid >> 6;         // wave -> 64-row emb strip
    const int lr   = lane & 15;
    const int g    = lane >> 4;
    const int lk   = g * 8;

    // per-lane row params (issued while staging is in flight)
    float  x2[4], crow[4];
    float* rowp[4];
    #pragma unroll
    for (int rf = 0; rf < 4; ++rf) {
        int xrow = wid * 64 + rf * 16 + lr;
        x2[rf]   = reinterpret_cast<const float*>(ws + WS_X2)[m0 + xrow];
        crow[rf] = reinterpret_cast<const float*>(ws + WS_CROW)[m0 + xrow];
        rowp[rf] = out + (size_t)(m0 + xrow) * NCON + n0;
    }

    __syncthreads();   // the ONLY barrier

    // ---------- MFMA: wave = 64 emb rows x 128 protos ----------
    bf16x8 xfrag[4][2];                // [rf][kk]
    #pragma unroll
    for (int rf = 0; rf < 4; ++rf) {
        int xrow = wid * 64 + rf * 16 + lr;
        #pragma unroll
        for (int kk = 0; kk < 2; ++kk) {
            int ke = (kk * 32 + lk) ^ ((xrow & 7) << 3);
            xfrag[rf][kk] = *reinterpret_cast<const bf16x8*>(&As[xrow * DIM + ke]);
        }
    }
    f32x4 acc[4][8] = {};              // [rf][pf]
    #pragma unroll
    for (int kk = 0; kk < 2; ++kk) {
        bf16x8 pfrag[8];
        #pragma unroll
        for (int pf = 0; pf < 8; ++pf) {
            int prow = pf * 16 + lr;
            int kep  = (kk * 32 + lk) ^ ((prow & 7) << 3);
            pfrag[pf] = *reinterpret_cast<const bf16x8*>(&Bs[prow * DIM + kep]);
        }
        #pragma unroll
        for (int pf = 0; pf < 8; ++pf)
            #pragma unroll
            for (int rf = 0; rf < 4; ++rf)
                acc[rf][pf] = __builtin_amdgcn_mfma_f32_16x16x32_bf16(
                    pfrag[pf], xfrag[rf][kk], acc[rf][pf], 0, 0, 0);
    }

    // ---------- epilogue: poly acosh + store (no barriers) ----------
    // D layout: col = lane&15 -> emb row (lr); row = g*4+j -> proto idx.
    // d = sqrt(tt) * P(tt), P cubic fit of acosh(1+t)/sqrt(t) on [0,4].
    const float* p2a = reinterpret_cast<const float*>(ws + WS_P2) + n0;
    const float* rpa = reinterpret_cast<const float*>(ws + WS_RP) + n0;
    #pragma unroll
    for (int pf = 0; pf < 8; ++pf) {
        int   col = pf * 16 + g * 4;
        f32x4 p2  = *reinterpret_cast<const f32x4*>(p2a + col);
        f32x4 rp  = *reinterpret_cast<const f32x4*>(rpa + col);
        #pragma unroll
        for (int rf = 0; rf < 4; ++rf) {
            f32x4 dv;
            #pragma unroll
            for (int j = 0; j < 4; ++j) {
                float sq = fmaxf(x2[rf] + p2[j] - 2.0f * acc[rf][pf][j], 0.0f);
                float tt = sq * (crow[rf] * rp[j]);
                float u  = __builtin_amdgcn_sqrtf(tt);
                float pl = fmaf(fmaf(fmaf(-0.0013415f, tt, 0.0164700f),
                                     tt, -0.1113059f),
                                tt, 1.4134377f);
                dv[j]    = u * pl;
            }
            *reinterpret_cast<f32x4*>(rowp[rf] + col) = dv;
        }
    }
}

extern "C" void kernel_launch(void* const* d_in, const int* in_sizes, int n_in,
                              void* d_out, int out_size, void* d_ws, size_t ws_size,
                              hipStream_t stream) {
    const float* emb   = (const float*)d_in[0];
    const float* proto = (const float*)d_in[1];
    float* out = (float*)d_out;
    char* ws   = (char*)d_ws;

    prepass_kernel<<<720, 256, 0, stream>>>(emb, proto, ws);    // 184320 threads
    poincare_pairwise_kernel<<<2048, 256, 0, stream>>>(ws, out); // 64 m x 32 n
}